// Round 1
// baseline (490.670 us; speedup 1.0000x reference)
//
#include <hip/hip_runtime.h>
#include <hip/hip_bf16.h>

#define EMBED 768
#define DIMQ  800
#define INC   1024
#define NPIX  1024   // GRID*GRID
#define AP    1032   // LDS pitch (bf16 elems) for the 32x1024 A tile

typedef __bf16 bf16_t;
typedef __bf16 bf16x8 __attribute__((ext_vector_type(8)));
typedef __bf16 bf16x2 __attribute__((ext_vector_type(2)));
typedef float  f32x4  __attribute__((ext_vector_type(4)));

// ---------------- K0: conv_w fp32 -> bf16 ----------------
__global__ void k_convert(const float* __restrict__ w, bf16_t* __restrict__ o, int n) {
    int i = blockIdx.x * 256 + threadIdx.x;
    if (i < n) o[i] = (bf16_t)w[i];
}

// ---------------- K1: q0t[i*32+b] = (Wq t0[b] + bq)[i] ----------------
// t0[b] = [cls(768), gender[b](32)]
__global__ void k_q0(const float* __restrict__ qkv_w, const float* __restrict__ qkv_b,
                     const float* __restrict__ cls, const float* __restrict__ gender,
                     float* __restrict__ q0t) {
    int i = blockIdx.x;          // 0..799
    int t = threadIdx.x;         // 64 threads (one wave)
    const float* row = qkv_w + (size_t)i * DIMQ;
    float ps = 0.f;
    for (int j = t; j < EMBED; j += 64) ps += row[j] * cls[j];
#pragma unroll
    for (int off = 1; off < 64; off <<= 1) ps += __shfl_xor(ps, off, 64);
    if (t < 32) {
        float g = 0.f;
#pragma unroll
        for (int j = 0; j < 32; ++j) g += row[EMBED + j] * gender[t * 32 + j];
        q0t[i * 32 + t] = ps + g + qkv_b[i];
    }
}

// ---------------- K2: u[b*768+j] = ln_g[j] * sum_o Wk[o][j] q0[b][o] ----------------
__global__ void k_u(const float* __restrict__ qkv_w, const float* __restrict__ q0t,
                    const float* __restrict__ ln_g, float* __restrict__ u) {
    int t = threadIdx.x;               // 256
    int b = t & 31, jj = t >> 5;       // 32 b x 8 j per block
    int j = blockIdx.x * 8 + jj;       // 0..767
    const float* wk = qkv_w + (size_t)DIMQ * DIMQ;   // rows 800..1599
    float acc = 0.f;
#pragma unroll 4
    for (int o = 0; o < DIMQ; ++o) acc += wk[(size_t)o * DIMQ + j] * q0t[o * 32 + b];
    u[b * EMBED + j] = acc * ln_g[j];
}

// ---------------- K3: fused conv-GEMM + row reductions -> scores ----------------
__global__ __launch_bounds__(256, 2)
void k_main(const float* __restrict__ x, const bf16_t* __restrict__ cw,
            const float* __restrict__ conv_b, const float* __restrict__ u,
            float* __restrict__ scores) {
    __shared__ bf16_t A_lds[32 * AP];
    __shared__ float  u_lds[EMBED];
    __shared__ float  part[4][32][3];
    __shared__ float  S_u_sh;

    const int tid = threadIdx.x;
    const int b   = blockIdx.x >> 5;
    const int hw0 = (blockIdx.x & 31) * 32;

    if (tid == 0) S_u_sh = 0.f;

    // stage u[b] into LDS, personal partial sum for S_u
    float psum = 0.f;
#pragma unroll
    for (int i = 0; i < 3; ++i) {
        float uv = u[b * EMBED + tid + i * 256];
        u_lds[tid + i * 256] = uv;
        psum += uv;
    }

    // stage A: x[b, c, hw0+m] -> A_lds[m][c] (bf16, transposed), coalesced global reads
    const float* xb = x + (size_t)b * (INC * NPIX) + hw0;
    const int m  = tid & 31;
    const int cp = tid >> 5;           // 0..7 (c-pair slot)
#pragma unroll 4
    for (int it = 0; it < 64; ++it) {
        int c = it * 16 + cp * 2;
        float x0 = xb[(size_t)c * NPIX + m];
        float x1 = xb[(size_t)c * NPIX + NPIX + m];
        bf16x2 pk; pk[0] = (bf16_t)x0; pk[1] = (bf16_t)x1;
        *(bf16x2*)&A_lds[m * AP + c] = pk;
    }
    __syncthreads();

    // S_u block reduction (read only after next barrier)
    {
        float w = psum;
#pragma unroll
        for (int off = 1; off < 64; off <<= 1) w += __shfl_xor(w, off, 64);
        if ((tid & 63) == 0) atomicAdd(&S_u_sh, w);
    }

    const int lane = tid & 63;
    const int wav  = tid >> 6;     // 0..3, owns o-slab [wav*192, wav*192+192)
    const int col  = lane & 15;
    const int quad = lane >> 4;

    const bf16_t* a0p = &A_lds[col * AP + quad * 8];
    const bf16_t* a1p = a0p + 16 * AP;

    float s1[2][4] = {}, s2[2][4] = {}, s3[2][4] = {};

    for (int pass = 0; pass < 4; ++pass) {
        const int o0 = wav * 192 + pass * 48;
        const bf16x8* bp0 = (const bf16x8*)(cw + (size_t)(o0 + col) * INC) + quad;
        const bf16x8* bp1 = (const bf16x8*)(cw + (size_t)(o0 + 16 + col) * INC) + quad;
        const bf16x8* bp2 = (const bf16x8*)(cw + (size_t)(o0 + 32 + col) * INC) + quad;
        f32x4 C[2][3] = {};
#pragma unroll 4
        for (int ks = 0; ks < 32; ++ks) {
            bf16x8 a0 = *(const bf16x8*)(a0p + ks * 32);
            bf16x8 a1 = *(const bf16x8*)(a1p + ks * 32);
            bf16x8 b0 = bp0[ks * 4];
            bf16x8 b1 = bp1[ks * 4];
            bf16x8 b2 = bp2[ks * 4];
            C[0][0] = __builtin_amdgcn_mfma_f32_16x16x32_bf16(a0, b0, C[0][0], 0, 0, 0);
            C[1][0] = __builtin_amdgcn_mfma_f32_16x16x32_bf16(a1, b0, C[1][0], 0, 0, 0);
            C[0][1] = __builtin_amdgcn_mfma_f32_16x16x32_bf16(a0, b1, C[0][1], 0, 0, 0);
            C[1][1] = __builtin_amdgcn_mfma_f32_16x16x32_bf16(a1, b1, C[1][1], 0, 0, 0);
            C[0][2] = __builtin_amdgcn_mfma_f32_16x16x32_bf16(a0, b2, C[0][2], 0, 0, 0);
            C[1][2] = __builtin_amdgcn_mfma_f32_16x16x32_bf16(a1, b2, C[1][2], 0, 0, 0);
        }
        // epilogue: C[mi][nn][r] = p[pixel = mi*16 + quad*4 + r][o = o0 + nn*16 + col]
        float uv0 = u_lds[o0 + col],      uv1 = u_lds[o0 + 16 + col],  uv2 = u_lds[o0 + 32 + col];
        float cb0 = conv_b[o0 + col],     cb1 = conv_b[o0 + 16 + col], cb2 = conv_b[o0 + 32 + col];
#pragma unroll
        for (int mi = 0; mi < 2; ++mi)
#pragma unroll
            for (int r = 0; r < 4; ++r) {
                float v0 = C[mi][0][r] + cb0;
                float v1 = C[mi][1][r] + cb1;
                float v2 = C[mi][2][r] + cb2;
                s1[mi][r] += v0 + v1 + v2;
                s2[mi][r] += v0 * v0 + v1 * v1 + v2 * v2;
                s3[mi][r] += v0 * uv0 + v1 * uv1 + v2 * uv2;
            }
    }

    // reduce across the 16 cols of each quad
#pragma unroll
    for (int mi = 0; mi < 2; ++mi)
#pragma unroll
        for (int r = 0; r < 4; ++r) {
            float a = s1[mi][r], bb = s2[mi][r], cc = s3[mi][r];
#pragma unroll
            for (int off = 1; off < 16; off <<= 1) {
                a  += __shfl_xor(a, off, 64);
                bb += __shfl_xor(bb, off, 64);
                cc += __shfl_xor(cc, off, 64);
            }
            if (col == 0) {
                int mm = mi * 16 + quad * 4 + r;
                part[wav][mm][0] = a; part[wav][mm][1] = bb; part[wav][mm][2] = cc;
            }
        }
    __syncthreads();

    if (tid < 32) {
        float S1 = 0.f, S2 = 0.f, S3 = 0.f;
#pragma unroll
        for (int w = 0; w < 4; ++w) {
            S1 += part[w][tid][0]; S2 += part[w][tid][1]; S3 += part[w][tid][2];
        }
        float mu  = S1 * (1.f / 768.f);
        float var = S2 * (1.f / 768.f) - mu * mu;
        float sc  = 0.035355339059327376f * (S3 - mu * S_u_sh) * rsqrtf(var + 1e-5f);
        scores[b * NPIX + hw0 + tid] = sc;
    }
}

// ---------------- K4: per-b softmax over 1024 scores ----------------
__global__ void k_softmax(const float* __restrict__ scores, float* __restrict__ out) {
    int b = blockIdx.x, t = threadIdx.x;   // 256 threads
    __shared__ float red[8];
    const float* s = scores + b * NPIX;
    float v[4];
    float mx = -1e30f;
#pragma unroll
    for (int i = 0; i < 4; ++i) { v[i] = s[t + i * 256]; mx = fmaxf(mx, v[i]); }
#pragma unroll
    for (int off = 1; off < 64; off <<= 1) mx = fmaxf(mx, __shfl_xor(mx, off, 64));
    if ((t & 63) == 0) red[t >> 6] = mx;
    __syncthreads();
    float M = fmaxf(fmaxf(red[0], red[1]), fmaxf(red[2], red[3]));
    float e[4]; float ss = 0.f;
#pragma unroll
    for (int i = 0; i < 4; ++i) { e[i] = __expf(v[i] - M); ss += e[i]; }
#pragma unroll
    for (int off = 1; off < 64; off <<= 1) ss += __shfl_xor(ss, off, 64);
    if ((t & 63) == 0) red[4 + (t >> 6)] = ss;
    __syncthreads();
    float inv = 1.f / (red[4] + red[5] + red[6] + red[7]);
#pragma unroll
    for (int i = 0; i < 4; ++i) out[b * NPIX + t + i * 256] = e[i] * inv;
}

extern "C" void kernel_launch(void* const* d_in, const int* in_sizes, int n_in,
                              void* d_out, int out_size, void* d_ws, size_t ws_size,
                              hipStream_t stream) {
    const float* x      = (const float*)d_in[0];
    const float* gender = (const float*)d_in[1];
    const float* conv_w = (const float*)d_in[2];
    const float* conv_b = (const float*)d_in[3];
    const float* ln_g   = (const float*)d_in[4];
    // d_in[5] = ln_b : drops out of softmax (constant per row)
    const float* cls    = (const float*)d_in[6];
    const float* qkv_w  = (const float*)d_in[7];
    const float* qkv_b  = (const float*)d_in[8];
    float* out = (float*)d_out;

    char* ws = (char*)d_ws;
    bf16_t* cw     = (bf16_t*)ws;                  // 768*1024*2       = 1572864 B
    float*  q0t    = (float*)(ws + 1572864);       // 800*32*4         = 102400 B
    float*  u      = (float*)(ws + 1675264);       // 32*768*4         = 98304 B
    float*  scores = (float*)(ws + 1773568);       // 32*1024*4        = 131072 B

    hipLaunchKernelGGL(k_convert, dim3(3072), dim3(256), 0, stream, conv_w, cw, EMBED * INC);
    hipLaunchKernelGGL(k_q0,      dim3(800),  dim3(64),  0, stream, qkv_w, qkv_b, cls, gender, q0t);
    hipLaunchKernelGGL(k_u,       dim3(96),   dim3(256), 0, stream, qkv_w, q0t, ln_g, u);
    hipLaunchKernelGGL(k_main,    dim3(1024), dim3(256), 0, stream, x, cw, conv_b, u, scores);
    hipLaunchKernelGGL(k_softmax, dim3(32),   dim3(256), 0, stream, scores, out);
}

// Round 2
// 379.082 us; speedup vs baseline: 1.2944x; 1.2944x over previous
//
#include <hip/hip_runtime.h>
#include <hip/hip_bf16.h>

#define EMBED 768
#define DIMQ  800
#define INC   1024
#define NPIX  1024
#define BM 128
#define BN 128
#define BK 64
#define RP 72          // padded LDS row (bf16 elems): 144 B -> conflict-free b128

typedef __bf16 bf16_t;
typedef __bf16 bf16x8 __attribute__((ext_vector_type(8)));
typedef float  f32x4  __attribute__((ext_vector_type(4)));

// ---------------- K0: conv_w fp32 -> bf16 ----------------
__global__ void k_convert(const float* __restrict__ w, bf16_t* __restrict__ o, int n) {
    int i = blockIdx.x * 256 + threadIdx.x;
    if (i < n) o[i] = (bf16_t)w[i];
}

// ---------------- K1: q0b[b*800+i] = (Wq t0[b] + bq)[i] ----------------
__global__ void k_q0(const float* __restrict__ qkv_w, const float* __restrict__ qkv_b,
                     const float* __restrict__ cls, const float* __restrict__ gender,
                     float* __restrict__ q0b) {
    int i = blockIdx.x;          // 0..799
    int t = threadIdx.x;         // 64 threads
    const float* row = qkv_w + (size_t)i * DIMQ;
    float ps = 0.f;
    for (int j = t; j < EMBED; j += 64) ps += row[j] * cls[j];
#pragma unroll
    for (int off = 1; off < 64; off <<= 1) ps += __shfl_xor(ps, off, 64);
    if (t < 32) {
        float g = 0.f;
#pragma unroll
        for (int j = 0; j < 32; ++j) g += row[EMBED + j] * gender[t * 32 + j];
        q0b[t * DIMQ + i] = ps + g + qkv_b[i];
    }
}

// ---------------- K2: u[b][j] = ln_g[j] * sum_o Wk[o][j] q0[b][o] ----------------
// grid = 32 b x 24 j-chunks; coalesced wk reads (32 consecutive j per load)
__global__ __launch_bounds__(256)
void k_u(const float* __restrict__ qkv_w, const float* __restrict__ q0b,
         const float* __restrict__ ln_g, float* __restrict__ u) {
    __shared__ float q0s[DIMQ];
    __shared__ float sh[8][33];
    int t = threadIdx.x;
    int b  = blockIdx.x / 24;
    int j0 = (blockIdx.x % 24) * 32;
    for (int i = t; i < DIMQ; i += 256) q0s[i] = q0b[b * DIMQ + i];
    __syncthreads();
    int j_l = t & 31, os = t >> 5;
    const float* wk = qkv_w + (size_t)DIMQ * DIMQ;
    const float* wp = wk + (size_t)(os * 100) * DIMQ + j0 + j_l;
    float acc = 0.f;
#pragma unroll 4
    for (int i = 0; i < 100; ++i) acc += wp[(size_t)i * DIMQ] * q0s[os * 100 + i];
    sh[os][j_l] = acc;
    __syncthreads();
    if (t < 32) {
        float s = 0.f;
#pragma unroll
        for (int o = 0; o < 8; ++o) s += sh[o][t];
        u[b * EMBED + j0 + t] = s * ln_g[j0 + t];
    }
}

// ---------------- K3: tiled GEMM (128x128xK=1024) + column reduction ----------------
// partial[(s*6+nt)*32768 + pixel] , s in {sum, sumsq, dot-u}
__global__ __launch_bounds__(256, 3)
void k_main(const float* __restrict__ x, const bf16_t* __restrict__ cw,
            const float* __restrict__ conv_b, const float* __restrict__ u,
            float* __restrict__ partial) {
    __shared__ bf16_t A_lds[BM * RP];
    __shared__ bf16_t B_lds[BN * RP];
    __shared__ float  part[2][BM][3];

    const int tid = threadIdx.x;
    // swizzle: siblings (same mt, 6 nt) share bi%8 -> same XCD, consecutive
    const int bi = blockIdx.x;
    const int c8 = bi & 7;
    const int j  = bi >> 3;
    const int nt = j % 6;
    const int mt = (j / 6) * 8 + c8;       // 0..255
    const int b   = mt >> 3;
    const int hw0 = (mt & 7) * BM;
    const int n0  = nt * BN;

    const float*  xb  = x  + (size_t)b  * (INC * NPIX) + hw0;   // x[b, c, hw0+m]
    const bf16_t* cwb = cw + (size_t)n0 * INC;

    const int lane = tid & 63;
    const int wav  = tid >> 6;
    const int col  = lane & 15;
    const int quad = lane >> 4;
    const int wm   = (wav >> 1) * 64;
    const int wn   = (wav & 1) * 64;

    // staging index precompute
    const int sm  = tid & 63;        // A: pixel within 64-half
    const int sco = tid >> 6;        // A: covers octs {2*sco, 2*sco+1}
    const int bn8 = tid >> 3;        // B: row (0..31), +32 per pass
    const int boc = tid & 7;         // B: k-octet

    f32x4 C[4][4] = {};

    for (int kt = 0; kt < 16; ++kt) {
        const int k0 = kt * BK;
        // ---- stage A: fp32 -> bf16, conflict-free padded rows ----
#pragma unroll
        for (int half = 0; half < 2; ++half) {
            const int m = sm + half * 64;
#pragma unroll
            for (int oi = 0; oi < 2; ++oi) {
                const int oct = sco * 2 + oi;
                const float* src = xb + (size_t)(k0 + oct * 8) * NPIX + m;
                bf16x8 pk;
#pragma unroll
                for (int jj = 0; jj < 8; ++jj) pk[jj] = (bf16_t)src[(size_t)jj * NPIX];
                *(bf16x8*)&A_lds[m * RP + oct * 8] = pk;
            }
        }
        // ---- stage B: bf16x8 loads (128 B coalesced per row) ----
#pragma unroll
        for (int pp = 0; pp < 4; ++pp) {
            const int n = bn8 + pp * 32;
            bf16x8 bv = *(const bf16x8*)(cwb + (size_t)n * INC + k0 + boc * 8);
            *(bf16x8*)&B_lds[n * RP + boc * 8] = bv;
        }
        __syncthreads();
        // ---- compute: 2 ks-steps x 16 MFMA ----
#pragma unroll
        for (int ks = 0; ks < 2; ++ks) {
            bf16x8 af[4], bg[4];
#pragma unroll
            for (int mi = 0; mi < 4; ++mi)
                af[mi] = *(const bf16x8*)&A_lds[(wm + mi * 16 + col) * RP + ks * 32 + quad * 8];
#pragma unroll
            for (int ni = 0; ni < 4; ++ni)
                bg[ni] = *(const bf16x8*)&B_lds[(wn + ni * 16 + col) * RP + ks * 32 + quad * 8];
#pragma unroll
            for (int mi = 0; mi < 4; ++mi)
#pragma unroll
                for (int ni = 0; ni < 4; ++ni)
                    C[mi][ni] = __builtin_amdgcn_mfma_f32_16x16x32_bf16(af[mi], bg[ni], C[mi][ni], 0, 0, 0);
        }
        __syncthreads();
    }

    // ---- epilogue: per-pixel s1,s2,s3 over this block's 128 columns ----
    float s1[4][4] = {}, s2[4][4] = {}, s3[4][4] = {};
#pragma unroll
    for (int ni = 0; ni < 4; ++ni) {
        const int og = n0 + wn + ni * 16 + col;
        const float cb = conv_b[og];
        const float uv = u[b * EMBED + og];
#pragma unroll
        for (int mi = 0; mi < 4; ++mi)
#pragma unroll
            for (int r = 0; r < 4; ++r) {
                float v = C[mi][ni][r] + cb;
                s1[mi][r] += v;
                s2[mi][r] += v * v;
                s3[mi][r] += v * uv;
            }
    }
#pragma unroll
    for (int mi = 0; mi < 4; ++mi)
#pragma unroll
        for (int r = 0; r < 4; ++r) {
            float a = s1[mi][r], bb = s2[mi][r], cc = s3[mi][r];
#pragma unroll
            for (int off = 1; off < 16; off <<= 1) {
                a  += __shfl_xor(a, off, 64);
                bb += __shfl_xor(bb, off, 64);
                cc += __shfl_xor(cc, off, 64);
            }
            if (col == 0) {
                int m = wm + mi * 16 + quad * 4 + r;
                part[wav & 1][m][0] = a;
                part[wav & 1][m][1] = bb;
                part[wav & 1][m][2] = cc;
            }
        }
    __syncthreads();
    if (tid < BM) {
        const size_t pix = (size_t)mt * BM + tid;
#pragma unroll
        for (int s = 0; s < 3; ++s)
            partial[(size_t)(s * 6 + nt) * 32768 + pix] = part[0][tid][s] + part[1][tid][s];
    }
}

// ---------------- K4: combine partials -> scores -> softmax ----------------
__global__ __launch_bounds__(1024)
void k_final(const float* __restrict__ partial, const float* __restrict__ u,
             float* __restrict__ out) {
    __shared__ float red[16];
    __shared__ float bc[3];
    const int b = blockIdx.x, t = threadIdx.x;
    const int lane = t & 63, wid = t >> 6;

    float pu = (t < EMBED) ? u[b * EMBED + t] : 0.f;
#pragma unroll
    for (int off = 1; off < 64; off <<= 1) pu += __shfl_xor(pu, off, 64);
    if (lane == 0) red[wid] = pu;
    __syncthreads();
    if (t == 0) { float s = 0.f; for (int i = 0; i < 16; ++i) s += red[i]; bc[0] = s; }
    __syncthreads();
    const float Su = bc[0];

    const size_t m = (size_t)b * 1024 + t;
    float S1 = 0.f, S2 = 0.f, S3 = 0.f;
#pragma unroll
    for (int nt = 0; nt < 6; ++nt) {
        S1 += partial[(size_t)(0 * 6 + nt) * 32768 + m];
        S2 += partial[(size_t)(1 * 6 + nt) * 32768 + m];
        S3 += partial[(size_t)(2 * 6 + nt) * 32768 + m];
    }
    const float mu  = S1 * (1.f / 768.f);
    const float var = S2 * (1.f / 768.f) - mu * mu;
    const float sc  = 0.035355339059327376f * (S3 - mu * Su) * rsqrtf(var + 1e-5f);

    float mx = sc;
#pragma unroll
    for (int off = 1; off < 64; off <<= 1) mx = fmaxf(mx, __shfl_xor(mx, off, 64));
    if (lane == 0) red[wid] = mx;
    __syncthreads();
    if (t == 0) { float mm = -1e30f; for (int i = 0; i < 16; ++i) mm = fmaxf(mm, red[i]); bc[1] = mm; }
    __syncthreads();
    const float e = __expf(sc - bc[1]);
    float ss = e;
#pragma unroll
    for (int off = 1; off < 64; off <<= 1) ss += __shfl_xor(ss, off, 64);
    __syncthreads();           // red[] reuse guard
    if (lane == 0) red[wid] = ss;
    __syncthreads();
    if (t == 0) { float s = 0.f; for (int i = 0; i < 16; ++i) s += red[i]; bc[2] = s; }
    __syncthreads();
    out[m] = e / bc[2];
}

extern "C" void kernel_launch(void* const* d_in, const int* in_sizes, int n_in,
                              void* d_out, int out_size, void* d_ws, size_t ws_size,
                              hipStream_t stream) {
    const float* x      = (const float*)d_in[0];
    const float* gender = (const float*)d_in[1];
    const float* conv_w = (const float*)d_in[2];
    const float* conv_b = (const float*)d_in[3];
    const float* ln_g   = (const float*)d_in[4];
    // d_in[5] = ln_b : drops out of softmax
    const float* cls    = (const float*)d_in[6];
    const float* qkv_w  = (const float*)d_in[7];
    const float* qkv_b  = (const float*)d_in[8];
    float* out = (float*)d_out;

    char* ws = (char*)d_ws;
    bf16_t* cw      = (bf16_t*)ws;                 // 1,572,864 B
    float*  q0b     = (float*)(ws + 1572864);      //   102,400 B
    float*  u       = (float*)(ws + 1675264);      //    98,304 B
    float*  partial = (float*)(ws + 1773568);      // 2,359,296 B (end 4,132,864)

    hipLaunchKernelGGL(k_convert, dim3(3072), dim3(256),  0, stream, conv_w, cw, EMBED * INC);
    hipLaunchKernelGGL(k_q0,      dim3(800),  dim3(64),   0, stream, qkv_w, qkv_b, cls, gender, q0b);
    hipLaunchKernelGGL(k_u,       dim3(768),  dim3(256),  0, stream, qkv_w, q0b, ln_g, u);
    hipLaunchKernelGGL(k_main,    dim3(1536), dim3(256),  0, stream, x, cw, conv_b, u, partial);
    hipLaunchKernelGGL(k_final,   dim3(32),   dim3(1024), 0, stream, partial, u, out);
}

// Round 3
// 365.773 us; speedup vs baseline: 1.3415x; 1.0364x over previous
//
#include <hip/hip_runtime.h>
#include <hip/hip_bf16.h>

#define EMBED 768
#define DIMQ  800
#define INC   1024
#define NPIX  1024

typedef __bf16 bf16_t;
typedef __bf16 bf16x8 __attribute__((ext_vector_type(8)));
typedef float  f32x4  __attribute__((ext_vector_type(4)));

#define GLD_LDS(gp, lp) __builtin_amdgcn_global_load_lds( \
    (const __attribute__((address_space(1))) void*)(gp),  \
    (__attribute__((address_space(3))) void*)(lp), 16, 0, 0)

// ---------------- K0: conv_w->bf16 convert  +  q0 rows  +  Su zero ----------------
__global__ __launch_bounds__(256)
void k_prep(const float* __restrict__ w, bf16_t* __restrict__ cw,
            const float* __restrict__ qkv_w, const float* __restrict__ qkv_b,
            const float* __restrict__ cls, const float* __restrict__ gender,
            float* __restrict__ q0b, float* __restrict__ Su) {
    const int bi = blockIdx.x;
    if (bi < 3072) {
        int i = bi * 256 + threadIdx.x;
        cw[i] = (bf16_t)w[i];
        if (bi == 0 && threadIdx.x < 32) Su[threadIdx.x] = 0.f;
    } else {
        const int wv = threadIdx.x >> 6, t = threadIdx.x & 63;
        const int i = (bi - 3072) * 4 + wv;           // qkv row 0..799
        const float* row = qkv_w + (size_t)i * DIMQ;
        float ps = 0.f;
        for (int j = t; j < EMBED; j += 64) ps += row[j] * cls[j];
#pragma unroll
        for (int off = 1; off < 64; off <<= 1) ps += __shfl_xor(ps, off, 64);
        if (t < 32) {
            float g = 0.f;
#pragma unroll
            for (int j = 0; j < 32; ++j) g += row[EMBED + j] * gender[t * 32 + j];
            q0b[t * DIMQ + i] = ps + g + qkv_b[i];
        }
    }
}

// ---------------- K1: u[b][j] = ln_g[j] * sum_o Wk[o][j] q0[b][o] ; Su[b] = sum_j u ----------------
__global__ __launch_bounds__(256)
void k_u(const float* __restrict__ qkv_w, const float* __restrict__ q0b,
         const float* __restrict__ ln_g, float* __restrict__ u, float* __restrict__ Su) {
    __shared__ float q0s[DIMQ];
    __shared__ float sh[8][33];
    int t = threadIdx.x;
    int b  = blockIdx.x / 24;
    int j0 = (blockIdx.x % 24) * 32;
    for (int i = t; i < DIMQ; i += 256) q0s[i] = q0b[b * DIMQ + i];
    __syncthreads();
    int j_l = t & 31, os = t >> 5;
    const float* wk = qkv_w + (size_t)DIMQ * DIMQ;
    const float* wp = wk + (size_t)(os * 100) * DIMQ + j0 + j_l;
    float acc = 0.f;
#pragma unroll 4
    for (int i = 0; i < 100; ++i) acc += wp[(size_t)i * DIMQ] * q0s[os * 100 + i];
    sh[os][j_l] = acc;
    __syncthreads();
    if (t < 32) {
        float s = 0.f;
#pragma unroll
        for (int o = 0; o < 8; ++o) s += sh[o][t];
        float uv = s * ln_g[j0 + t];
        u[b * EMBED + j0 + t] = uv;
        float ss = uv;
#pragma unroll
        for (int off = 1; off < 32; off <<= 1) ss += __shfl_xor(ss, off, 64);
        if (t == 0) atomicAdd(&Su[b], ss);
    }
}

// ---------------- K2: full-N GEMM per block (64 pixels x 768 out x K=1024) ----------------
// A (64x1024 bf16) resident in LDS for all 6 nt-passes -> x read ONCE from HBM.
// B staged per (nt,kt) via async global_load_lds, XOR-octet swizzle (no padding).
__global__ __launch_bounds__(512, 2)
void k_main(const float* __restrict__ x, const bf16_t* __restrict__ cw,
            const float* __restrict__ conv_b, const float* __restrict__ u,
            const float* __restrict__ Su, float* __restrict__ scores) {
    __shared__ __align__(16) unsigned char lds[163840];
    // A: 64 rows x 2048 B (k-octets XOR-swizzled by row&7)     @ 0
    // B: 128 rows x 256 B (k-octets XOR-swizzled by row&7)     @ 131072
    bf16_t* B_lds = (bf16_t*)(lds + 131072);

    const int tid = threadIdx.x;
    const int mt  = blockIdx.x;           // 0..511
    const int b   = mt >> 4;              // 32 batches
    const int hw0 = (mt & 15) * 64;       // 16 pixel-strips of 64

    // ---- stage A: transpose x[b, k, hw0+m] -> A[m][k] bf16, full K ----
    const int am = tid & 63;
    const int kg = tid >> 6;              // wave id = k-slab 0..7
    const float* xs = x + (size_t)b * (INC * NPIX) + hw0 + am;
#pragma unroll 4
    for (int i = 0; i < 16; ++i) {
        const int o = kg * 16 + i;        // k-octet 0..127
        bf16x8 pk;
#pragma unroll
        for (int j = 0; j < 8; ++j) pk[j] = (bf16_t)xs[(size_t)(o * 8 + j) * NPIX];
        const int osw = (o & ~7) | ((o ^ am) & 7);
        *(bf16x8*)(lds + am * 2048 + osw * 16) = pk;
    }

    const int lane = tid & 63;
    const int wav  = tid >> 6;
    const int col  = lane & 15;
    const int quad = lane >> 4;
    const int wm   = (wav >> 2) * 32;     // 2-way M split
    const int wn   = (wav & 3) * 32;      // 4-way N split

    // B-staging lane mapping: each instr covers 4 rows x 16 octets
    const int brow0 = wav * 16 + (lane >> 4);
    const int bop   = lane & 15;

    float rs1[2][4] = {}, rs2[2][4] = {}, rs3[2][4] = {};

    __syncthreads();   // A ready

    for (int nt = 0; nt < 6; ++nt) {
        float cbv[2], uvv[2];
#pragma unroll
        for (int ni = 0; ni < 2; ++ni) {
            const int og = nt * 128 + wn + ni * 16 + col;
            cbv[ni] = conv_b[og];
            uvv[ni] = u[b * EMBED + og];
        }
        f32x4 C[2][2] = {};
        for (int kt = 0; kt < 8; ++kt) {
            // ---- async stage B(nt,kt): 128 rows x 128 k bf16 = 32 KB ----
#pragma unroll
            for (int p = 0; p < 4; ++p) {
                const int n = brow0 + p * 4;
                const int o = (bop & 8) | ((bop ^ n) & 7);   // permuted source octet
                const bf16_t* gp = cw + (size_t)(nt * 128 + n) * INC + kt * 128 + o * 8;
                GLD_LDS(gp, B_lds + (wav * 16 + p * 4) * 128);
            }
            __syncthreads();   // drains vmcnt -> B visible
            // ---- compute: 4 ks-steps x 4 MFMA ----
#pragma unroll
            for (int ks = 0; ks < 4; ++ks) {
                bf16x8 af[2], bg[2];
#pragma unroll
                for (int mi = 0; mi < 2; ++mi) {
                    const int row = wm + mi * 16 + col;
                    const int o   = kt * 16 + ks * 4 + quad;
                    const int osw = (o & ~7) | ((o ^ row) & 7);
                    af[mi] = *(const bf16x8*)(lds + row * 2048 + osw * 16);
                }
#pragma unroll
                for (int ni = 0; ni < 2; ++ni) {
                    const int n   = wn + ni * 16 + col;
                    const int o   = ks * 4 + quad;
                    const int osw = (o & 8) | ((o ^ n) & 7);
                    bg[ni] = *(const bf16x8*)(lds + 131072 + n * 256 + osw * 16);
                }
#pragma unroll
                for (int mi = 0; mi < 2; ++mi)
#pragma unroll
                    for (int ni = 0; ni < 2; ++ni)
                        C[mi][ni] = __builtin_amdgcn_mfma_f32_16x16x32_bf16(af[mi], bg[ni], C[mi][ni], 0, 0, 0);
            }
            __syncthreads();   // protect B before restage
        }
        // ---- epilogue for this nt: fold 32 cols into per-row sums ----
#pragma unroll
        for (int mi = 0; mi < 2; ++mi)
#pragma unroll
            for (int r = 0; r < 4; ++r) {
                float v0 = C[mi][0][r] + cbv[0];
                float v1 = C[mi][1][r] + cbv[1];
                float a = v0 + v1;
                float s = v0 * v0 + v1 * v1;
                float d = v0 * uvv[0] + v1 * uvv[1];
#pragma unroll
                for (int off = 1; off < 16; off <<= 1) {
                    a += __shfl_xor(a, off, 64);
                    s += __shfl_xor(s, off, 64);
                    d += __shfl_xor(d, off, 64);
                }
                rs1[mi][r] += a; rs2[mi][r] += s; rs3[mi][r] += d;
            }
    }

    // ---- final: cross-wave combine (reuse B LDS), write scores ----
    __syncthreads();
    float* part = (float*)(lds + 131072);   // [8 waves][32 rows][3]
    if (col == 0) {
#pragma unroll
        for (int mi = 0; mi < 2; ++mi)
#pragma unroll
            for (int r = 0; r < 4; ++r) {
                const int rr = mi * 16 + quad * 4 + r;
                part[(wav * 32 + rr) * 3 + 0] = rs1[mi][r];
                part[(wav * 32 + rr) * 3 + 1] = rs2[mi][r];
                part[(wav * 32 + rr) * 3 + 2] = rs3[mi][r];
            }
    }
    __syncthreads();
    if (tid < 64) {
        const int half = tid >> 5, r32 = tid & 31;
        float S1 = 0.f, S2 = 0.f, S3 = 0.f;
#pragma unroll
        for (int w = 0; w < 4; ++w) {
            const int base = ((half * 4 + w) * 32 + r32) * 3;
            S1 += part[base]; S2 += part[base + 1]; S3 += part[base + 2];
        }
        const float mu  = S1 * (1.f / 768.f);
        const float var = S2 * (1.f / 768.f) - mu * mu;
        const float sc  = 0.035355339059327376f * (S3 - mu * Su[b]) * rsqrtf(var + 1e-5f);
        scores[b * NPIX + hw0 + tid] = sc;
    }
}

// ---------------- K3: per-b softmax over 1024 scores ----------------
__global__ __launch_bounds__(1024)
void k_final(const float* __restrict__ scores, float* __restrict__ out) {
    __shared__ float red[16];
    __shared__ float bc[2];
    const int b = blockIdx.x, t = threadIdx.x;
    const int lane = t & 63, wid = t >> 6;
    const float sc = scores[b * NPIX + t];

    float mx = sc;
#pragma unroll
    for (int off = 1; off < 64; off <<= 1) mx = fmaxf(mx, __shfl_xor(mx, off, 64));
    if (lane == 0) red[wid] = mx;
    __syncthreads();
    if (t == 0) { float mm = -1e30f; for (int i = 0; i < 16; ++i) mm = fmaxf(mm, red[i]); bc[0] = mm; }
    __syncthreads();
    const float e = __expf(sc - bc[0]);
    float ss = e;
#pragma unroll
    for (int off = 1; off < 64; off <<= 1) ss += __shfl_xor(ss, off, 64);
    __syncthreads();
    if (lane == 0) red[wid] = ss;
    __syncthreads();
    if (t == 0) { float s = 0.f; for (int i = 0; i < 16; ++i) s += red[i]; bc[1] = s; }
    __syncthreads();
    out[b * NPIX + t] = e / bc[1];
}

extern "C" void kernel_launch(void* const* d_in, const int* in_sizes, int n_in,
                              void* d_out, int out_size, void* d_ws, size_t ws_size,
                              hipStream_t stream) {
    const float* x      = (const float*)d_in[0];
    const float* gender = (const float*)d_in[1];
    const float* conv_w = (const float*)d_in[2];
    const float* conv_b = (const float*)d_in[3];
    const float* ln_g   = (const float*)d_in[4];
    // d_in[5] = ln_b : drops out of softmax
    const float* cls    = (const float*)d_in[6];
    const float* qkv_w  = (const float*)d_in[7];
    const float* qkv_b  = (const float*)d_in[8];
    float* out = (float*)d_out;

    char* ws = (char*)d_ws;
    bf16_t* cw     = (bf16_t*)ws;                  // 1,572,864 B
    float*  q0b    = (float*)(ws + 1572864);       //   102,400 B
    float*  u      = (float*)(ws + 1675264);       //    98,304 B
    float*  Su     = (float*)(ws + 1773568);       //       128 B
    float*  scores = (float*)(ws + 1773696);       //   131,072 B

    hipLaunchKernelGGL(k_prep,  dim3(3272), dim3(256),  0, stream,
                       conv_w, cw, qkv_w, qkv_b, cls, gender, q0b, Su);
    hipLaunchKernelGGL(k_u,     dim3(768),  dim3(256),  0, stream, qkv_w, q0b, ln_g, u, Su);
    hipLaunchKernelGGL(k_main,  dim3(512),  dim3(512),  0, stream, x, cw, conv_b, u, Su, scores);
    hipLaunchKernelGGL(k_final, dim3(32),   dim3(1024), 0, stream, scores, out);
}

// Round 5
// 303.901 us; speedup vs baseline: 1.6146x; 1.2036x over previous
//
#include <hip/hip_runtime.h>
#include <hip/hip_bf16.h>

#define EMBED 768
#define DIMQ  800
#define INC   1024
#define NPIX  1024

typedef __bf16 bf16_t;
typedef __bf16 bf16x8 __attribute__((ext_vector_type(8)));
typedef __bf16 bf16x2 __attribute__((ext_vector_type(2)));
typedef float  f32x4  __attribute__((ext_vector_type(4)));

#define GLD_LDS(gp, lp) __builtin_amdgcn_global_load_lds( \
    (const __attribute__((address_space(1))) void*)(gp),  \
    (__attribute__((address_space(3))) void*)(lp), 16, 0, 0)

// ---------------- K0: x transpose->bf16 (oct-permuted) + cw convert (oct-permuted) + q0 ----------------
// xT[b][m][k] with k-octet slot = oct ^ (m&7) within each 64k group; cw same with (n&7).
__global__ __launch_bounds__(256)
void k_prep(const float* __restrict__ x, bf16_t* __restrict__ xT,
            const float* __restrict__ w, bf16_t* __restrict__ cw,
            const float* __restrict__ qkv_w, const float* __restrict__ qkv_b,
            const float* __restrict__ cls, const float* __restrict__ gender,
            float* __restrict__ q0b) {
    __shared__ __align__(16) unsigned int tile[64 * 36];   // 64 m-rows x (32 dw + 4 pad)
    const int bi = blockIdx.x;
    const int t  = threadIdx.x;
    if (bi < 8192) {
        // ---- transpose one (b, 64k, 64m) tile ----
        const int b  = bi >> 8;
        const int k0 = ((bi >> 4) & 15) * 64;
        const int m0 = (bi & 15) * 64;
        const int m_l = t & 63;
        const int wv  = t >> 6;
        const float* src = x + ((size_t)(b * 1024 + k0 + wv * 16) * 1024) + m0 + m_l;
        bf16x2* trow = (bf16x2*)tile;
#pragma unroll
        for (int i = 0; i < 8; ++i) {
            float a0 = src[(size_t)(2 * i) * 1024];
            float a1 = src[(size_t)(2 * i + 1) * 1024];
            bf16x2 p; p[0] = (bf16_t)a0; p[1] = (bf16_t)a1;
            trow[m_l * 36 + wv * 8 + i] = p;     // dw: m*36 + wv*8 + i  (stride 36 dw!)
        }
        __syncthreads();
        const int m_r = t >> 2;
        bf16_t* drow = xT + ((size_t)(b * 1024 + m0 + m_r) * 1024) + k0;
#pragma unroll
        for (int rep = 0; rep < 2; ++rep) {
            int j = (t & 3) + rep * 4;
            bf16x8 v = *(const bf16x8*)&tile[m_r * 36 + j * 4];
            int slot = j ^ (m_r & 7);
            *(bf16x8*)(drow + slot * 8) = v;
        }
    } else if (bi < 8392) {
        // ---- q0b[b*800+i] = (Wq t0[b] + bq)[i] ----
        const int wv = t >> 6, tl = t & 63;
        const int i = (bi - 8192) * 4 + wv;           // 0..799
        const float* row = qkv_w + (size_t)i * DIMQ;
        float ps = 0.f;
        for (int j = tl; j < EMBED; j += 64) ps += row[j] * cls[j];
#pragma unroll
        for (int off = 1; off < 64; off <<= 1) ps += __shfl_xor(ps, off, 64);
        if (tl < 32) {
            float g = 0.f;
#pragma unroll
            for (int j = 0; j < 32; ++j) g += row[EMBED + j] * gender[tl * 32 + j];
            q0b[tl * DIMQ + i] = ps + g + qkv_b[i];
        }
    } else {
        // ---- cw convert, oct slot = j ^ (n&7) ----
        const int i = (bi - 8392) * 256 + t;          // dst flat index
        const int n = i >> 10, k = i & 1023;
        const int s = (k >> 3) & 7;
        const int src_k = (k & ~63) | (((s ^ (n & 7)) & 7) << 3) | (k & 7);
        cw[i] = (bf16_t)w[(size_t)n * 1024 + src_k];
    }
}

// ---------------- K1: u[b][j] = ln_g[j] * sum_o Wk[o][j] q0[b][o] ----------------
__global__ __launch_bounds__(256)
void k_u(const float* __restrict__ qkv_w, const float* __restrict__ q0b,
         const float* __restrict__ ln_g, float* __restrict__ u) {
    __shared__ float q0s[DIMQ];
    __shared__ float sh[8][33];
    int t = threadIdx.x;
    int b  = blockIdx.x / 24;
    int j0 = (blockIdx.x % 24) * 32;
    for (int i = t; i < DIMQ; i += 256) q0s[i] = q0b[b * DIMQ + i];
    __syncthreads();
    int j_l = t & 31, os = t >> 5;
    const float* wk = qkv_w + (size_t)DIMQ * DIMQ;
    const float* wp = wk + (size_t)(os * 100) * DIMQ + j0 + j_l;
    float acc = 0.f;
#pragma unroll 4
    for (int i = 0; i < 100; ++i) acc += wp[(size_t)i * DIMQ] * q0s[os * 100 + i];
    sh[os][j_l] = acc;
    __syncthreads();
    if (t < 32) {
        float s = 0.f;
#pragma unroll
        for (int o = 0; o < 8; ++o) s += sh[o][t];
        u[b * EMBED + j0 + t] = s * ln_g[j0 + t];
    }
}

// ---------------- K2: 128x128xK1024 GEMM tile + column reduction ----------------
__global__ __launch_bounds__(256, 3)
void k_main(const bf16_t* __restrict__ xT, const bf16_t* __restrict__ cw,
            const float* __restrict__ conv_b, const float* __restrict__ u,
            float* __restrict__ partial) {
    __shared__ __align__(1024) unsigned char smem[32768 + 3072];
    // A: 128 rows x 128 B @0 ; B: same @16384 ; part: 2x128x3 f32 @32768

    const int tid = threadIdx.x;
    // XCD swizzle: x8 = bi&7 -> XCD; sibling nt's consecutive on same XCD
    const int bi = blockIdx.x;
    const int x8 = bi & 7;
    const int s  = bi >> 3;
    const int nt = s % 6;
    const int mt = (s / 6) * 8 + x8;        // 0..255
    const int b  = mt >> 3;
    const int gm = mt * 128;                // global pixel row
    const int gn = nt * 128;                // global out-channel

    const int wv = tid >> 6;
    const int l  = tid & 63;
    const int lr = l >> 3;                  // row-in-8 for staging
    const int lc = l & 7;                   // oct slot for staging

    const int lane = l;
    const int col  = lane & 15;
    const int quad = lane >> 4;
    const int wm   = (wv >> 1) * 64;
    const int wn   = (wv & 1) * 64;

    bf16_t* A = (bf16_t*)smem;
    bf16_t* B = (bf16_t*)(smem + 16384);

    f32x4 C[4][4] = {};

    for (int kt = 0; kt < 16; ++kt) {
        const int ko = kt * 64;
        // ---- stage A+B via async DMA, linear lane mapping (swizzle pre-baked) ----
#pragma unroll
        for (int p = 0; p < 4; ++p) {
            const int r = p * 32 + wv * 8 + lr;
            GLD_LDS(xT + (size_t)(gm + r) * 1024 + ko + lc * 8, A + (p * 32 + wv * 8) * 64);
            GLD_LDS(cw + (size_t)(gn + r) * 1024 + ko + lc * 8, B + (p * 32 + wv * 8) * 64);
        }
        __syncthreads();
        // ---- 2 ks x 16 MFMA ----
#pragma unroll
        for (int ks = 0; ks < 2; ++ks) {
            bf16x8 af[4], bg[4];
#pragma unroll
            for (int mi = 0; mi < 4; ++mi) {
                const int r  = wm + mi * 16 + col;
                const int ph = (ks * 4 + quad) ^ (r & 7);
                af[mi] = *(const bf16x8*)(A + r * 64 + ph * 8);
            }
#pragma unroll
            for (int ni = 0; ni < 4; ++ni) {
                const int r  = wn + ni * 16 + col;
                const int ph = (ks * 4 + quad) ^ (r & 7);
                bg[ni] = *(const bf16x8*)(B + r * 64 + ph * 8);
            }
#pragma unroll
            for (int mi = 0; mi < 4; ++mi)
#pragma unroll
                for (int ni = 0; ni < 4; ++ni)
                    C[mi][ni] = __builtin_amdgcn_mfma_f32_16x16x32_bf16(af[mi], bg[ni], C[mi][ni], 0, 0, 0);
        }
        __syncthreads();
    }

    // ---- epilogue: fold 128 cols -> per-pixel (s1,s2,s3) partials ----
    float cb[4], uv[4];
#pragma unroll
    for (int ni = 0; ni < 4; ++ni) {
        const int og = gn + wn + ni * 16 + col;
        cb[ni] = conv_b[og];
        uv[ni] = u[b * EMBED + og];
    }
    float* part = (float*)(smem + 32768);   // [2 n-halves][128 rows][3]
#pragma unroll
    for (int mi = 0; mi < 4; ++mi)
#pragma unroll
        for (int r = 0; r < 4; ++r) {
            float a = 0.f, sq = 0.f, d = 0.f;
#pragma unroll
            for (int ni = 0; ni < 4; ++ni) {
                float v = C[mi][ni][r] + cb[ni];
                a += v; sq += v * v; d += v * uv[ni];
            }
#pragma unroll
            for (int off = 1; off < 16; off <<= 1) {
                a  += __shfl_xor(a, off, 64);
                sq += __shfl_xor(sq, off, 64);
                d  += __shfl_xor(d, off, 64);
            }
            if (col == 0) {
                const int row = wm + mi * 16 + quad * 4 + r;
                float* pp = part + ((wv & 1) * 128 + row) * 3;
                pp[0] = a; pp[1] = sq; pp[2] = d;
            }
        }
    __syncthreads();
    if (tid < 128) {
        const float* p0 = part + tid * 3;
        const float* p1 = part + (128 + tid) * 3;
        const size_t pix = (size_t)gm + tid;
        partial[(size_t)(0 * 6 + nt) * 32768 + pix] = p0[0] + p1[0];
        partial[(size_t)(1 * 6 + nt) * 32768 + pix] = p0[1] + p1[1];
        partial[(size_t)(2 * 6 + nt) * 32768 + pix] = p0[2] + p1[2];
    }
}

// ---------------- K3: combine partials -> scores -> softmax ----------------
__global__ __launch_bounds__(1024)
void k_final(const float* __restrict__ partial, const float* __restrict__ u,
             float* __restrict__ out) {
    __shared__ float red[16];
    __shared__ float bc[3];
    const int b = blockIdx.x, t = threadIdx.x;
    const int lane = t & 63, wid = t >> 6;

    float pu = (t < EMBED) ? u[b * EMBED + t] : 0.f;
#pragma unroll
    for (int off = 1; off < 64; off <<= 1) pu += __shfl_xor(pu, off, 64);
    if (lane == 0) red[wid] = pu;
    __syncthreads();
    if (t == 0) { float s = 0.f; for (int i = 0; i < 16; ++i) s += red[i]; bc[0] = s; }
    __syncthreads();
    const float Su = bc[0];

    const size_t m = (size_t)b * 1024 + t;
    float S1 = 0.f, S2 = 0.f, S3 = 0.f;
#pragma unroll
    for (int nt = 0; nt < 6; ++nt) {
        S1 += partial[(size_t)(0 * 6 + nt) * 32768 + m];
        S2 += partial[(size_t)(1 * 6 + nt) * 32768 + m];
        S3 += partial[(size_t)(2 * 6 + nt) * 32768 + m];
    }
    const float mu  = S1 * (1.f / 768.f);
    const float var = S2 * (1.f / 768.f) - mu * mu;
    const float sc  = 0.035355339059327376f * (S3 - mu * Su) * rsqrtf(var + 1e-5f);

    float mx = sc;
#pragma unroll
    for (int off = 1; off < 64; off <<= 1) mx = fmaxf(mx, __shfl_xor(mx, off, 64));
    if (lane == 0) red[wid] = mx;
    __syncthreads();
    if (t == 0) { float mm = -1e30f; for (int i = 0; i < 16; ++i) mm = fmaxf(mm, red[i]); bc[1] = mm; }
    __syncthreads();
    const float e = __expf(sc - bc[1]);
    float ss = e;
#pragma unroll
    for (int off = 1; off < 64; off <<= 1) ss += __shfl_xor(ss, off, 64);
    __syncthreads();
    if (lane == 0) red[wid] = ss;
    __syncthreads();
    if (t == 0) { float s = 0.f; for (int i = 0; i < 16; ++i) s += red[i]; bc[2] = s; }
    __syncthreads();
    out[m] = e / bc[2];
}

extern "C" void kernel_launch(void* const* d_in, const int* in_sizes, int n_in,
                              void* d_out, int out_size, void* d_ws, size_t ws_size,
                              hipStream_t stream) {
    const float* x      = (const float*)d_in[0];
    const float* gender = (const float*)d_in[1];
    const float* conv_w = (const float*)d_in[2];
    const float* conv_b = (const float*)d_in[3];
    const float* ln_g   = (const float*)d_in[4];
    // d_in[5] = ln_b : drops out of softmax
    const float* cls    = (const float*)d_in[6];
    const float* qkv_w  = (const float*)d_in[7];
    const float* qkv_b  = (const float*)d_in[8];
    float* out = (float*)d_out;

    char* ws = (char*)d_ws;
    bf16_t* cw      = (bf16_t*)ws;                 //  1,572,864 B
    float*  q0b     = (float*)(ws + 1572864);      //    102,400 B
    float*  u       = (float*)(ws + 1675264);      //     98,304 B
    float*  partial = (float*)(ws + 1773568);      //  2,359,296 B
    bf16_t* xT      = (bf16_t*)(ws + 4132864);     // 67,108,864 B (end ~71.2 MB)

    hipLaunchKernelGGL(k_prep,  dim3(11464), dim3(256),  0, stream,
                       x, xT, conv_w, cw, qkv_w, qkv_b, cls, gender, q0b);
    hipLaunchKernelGGL(k_u,     dim3(768),   dim3(256),  0, stream, qkv_w, q0b, ln_g, u);
    hipLaunchKernelGGL(k_main,  dim3(1536),  dim3(256),  0, stream, xT, cw, conv_b, u, partial);
    hipLaunchKernelGGL(k_final, dim3(32),    dim3(1024), 0, stream, partial, u, out);
}